// Round 3
// baseline (11140.371 us; speedup 1.0000x reference)
//
#include <hip/hip_runtime.h>
#include <hip/hip_bf16.h>

typedef unsigned short u16;
typedef unsigned long long ull;
typedef __attribute__((ext_vector_type(8))) short bf16x8;
typedef __attribute__((ext_vector_type(4))) float f32x4;
typedef __attribute__((ext_vector_type(2))) float f32x2;

// Problem sizes
#define HID 1024
#define BATCH 64
#define SEQ 512
#define MTOK 32768   // SEQ*BATCH

// Workspace layout (bytes)
#define WB_WIH0 0
#define WB_WHH0 4194304
#define WB_WIH1 8388608
#define WB_WHH1 12582912
#define WS_X_OFF   33554432ull           // X buffer (bf16, 32768x1024)
#define WS_XP_OFF  100663296ull          // Xproj layer0 (bf16, packed layout)
#define WS_NEEDED  369098752ull
// Rings + flags overlay the Wih0 bf16 byte region [0, 8M), dead after gemm0:
#define RING0_B 0ull          // 4 slots x 64x1024 bf16 = 512 KB
#define RING1_B 524288ull     // 4 slots x 64x1024 bf16
#define FLAGS_B 3145728ull    // F0[64], Fr[64]

// Output layout (fp32 elements)
#define OUT_H_OFF 33554432
#define OUT_C_OFF 33685504

// Packed per-thread gate-tile layout for Xp:
//   elem(r, jblk, tid, gg, bb, u) = r*262144 + jblk*4096 + tid*16 + gg*4 + bb*2 + u
// where consumer thread tid = bp*8+up handles batches bp*2+bb, cols j0+up*2+u.

__device__ __forceinline__ u16 f2bf(float f) {
    union { float f; unsigned u; } x; x.f = f;
    unsigned r = (x.u + 0x7FFFu + ((x.u >> 16) & 1u)) >> 16;
    return (u16)r;
}
__device__ __forceinline__ float bf2f(u16 v) {
    union { unsigned u; float f; } x; x.u = ((unsigned)v) << 16;
    return x.f;
}
__device__ __forceinline__ float fexp2(float x) { return __builtin_amdgcn_exp2f(x); }
__device__ __forceinline__ float frcp(float x) { return __builtin_amdgcn_rcpf(x); }
__device__ __forceinline__ float sigm(float x) {
    return frcp(1.f + fexp2(x * -1.4426950408889634f));
}
__device__ __forceinline__ float tanh_f(float x) {
    return 1.f - 2.f * frcp(fexp2(x * 2.8853900817779268f) + 1.f);
}
__device__ __forceinline__ float xpick(ull q, int bb, int u) {
    return bf2f((u16)(q >> ((bb * 2 + u) << 4)));
}
__device__ __forceinline__ void ldsload16(const u16* g, u16* l) {
    __builtin_amdgcn_global_load_lds(
        (__attribute__((address_space(1))) void*)(unsigned long long)(const char*)g,
        (__attribute__((address_space(3))) void*)l, 16, 0, 0);
}
__device__ __forceinline__ ull ld8(const ull* p) {
    return __hip_atomic_load(p, __ATOMIC_RELAXED, __HIP_MEMORY_SCOPE_AGENT);
}
__device__ __forceinline__ unsigned ld4(const unsigned* p) {
    return __hip_atomic_load(p, __ATOMIC_RELAXED, __HIP_MEMORY_SCOPE_AGENT);
}
__device__ __forceinline__ void st8(ull* p, ull v) {
    __hip_atomic_store(p, v, __ATOMIC_RELAXED, __HIP_MEMORY_SCOPE_AGENT);
}
__device__ __forceinline__ void st4(unsigned* p, unsigned v) {
    __hip_atomic_store(p, v, __ATOMIC_RELAXED, __HIP_MEMORY_SCOPE_AGENT);
}

// ---------------- prep: weights fp32->bf16 ----------------
__launch_bounds__(256)
__global__ void prep_weights(const float* __restrict__ a, const float* __restrict__ b,
                             const float* __restrict__ c, const float* __restrict__ d,
                             u16* __restrict__ dst) {
    const int gtid = blockIdx.x * 256 + threadIdx.x;
#pragma unroll
    for (int k = 0; k < 16; k++) {
        const float* s = (k < 4) ? a : (k < 8) ? b : (k < 12) ? c : d;
        const int off = ((k & 3) * 262144 + gtid) * 4;
        float4 v = *(const float4*)(s + off);
        ushort4 o;
        o.x = f2bf(v.x); o.y = f2bf(v.y); o.z = f2bf(v.z); o.w = f2bf(v.w);
        *(ushort4*)(dst + (size_t)(k >> 2) * 4194304 + off) = o;
    }
}

// ---------------- embedding gather ----------------
__launch_bounds__(256)
__global__ void gather_x(const int* __restrict__ y, const float* __restrict__ E,
                         u16* __restrict__ X) {
    const int m = blockIdx.x;
    const int t = m >> 6, b = m & 63;
    const int idx = y[b * SEQ + t];
    const float4 v = *(const float4*)(E + (size_t)idx * HID + threadIdx.x * 4);
    ushort4 o;
    o.x = f2bf(v.x); o.y = f2bf(v.y); o.z = f2bf(v.z); o.w = f2bf(v.w);
    *(ushort4*)(X + (size_t)m * HID + threadIdx.x * 4) = o;
}

// ---------------- big GEMM (layer0 input projection) ----------------
// Writes C in the packed per-thread layout consumed by the L0 recurrence.
__launch_bounds__(256, 3)
__global__ void gemm_bt(const u16* __restrict__ A, const u16* __restrict__ Bm,
                        const float* __restrict__ bias, u16* __restrict__ C,
                        int M, int N, int K) {
    __shared__ u16 As[128 * 64];
    __shared__ u16 Bs[128 * 64];
    const int tid = threadIdx.x;
    const int ln = tid & 63;
    const int l15 = ln & 15, q = ln >> 4;
    const int w = tid >> 6;
    const int wm = (w & 1) * 64, wn = (w >> 1) * 64;
    const int m0 = blockIdx.y * 128, n0 = blockIdx.x * 128;

    f32x4 acc[4][4];
#pragma unroll
    for (int i = 0; i < 4; i++)
#pragma unroll
        for (int j = 0; j < 4; j++) acc[i][j] = 0.f;

    const int srow = tid >> 3;
    const int spk = tid & 7;
    const u16* gA = A + (size_t)m0 * K;
    const u16* gB = Bm + (size_t)n0 * K;
    const int wbase = (tid & 0xC0) * 8;

    const int kIters = K >> 6;
    for (int kt = 0; kt < kIters; kt++) {
        const int k0 = kt << 6;
        __syncthreads();
#pragma unroll
        for (int i = 0; i < 4; i++) {
            const int row = i * 32 + srow;
            const int kb = spk ^ (row & 7);
            ldsload16(gA + (size_t)row * K + k0 + kb * 8, &As[i * 2048 + wbase]);
            ldsload16(gB + (size_t)row * K + k0 + kb * 8, &Bs[i * 2048 + wbase]);
        }
        __syncthreads();
#pragma unroll
        for (int s = 0; s < 2; s++) {
            const int xk = ((s * 4 + q) ^ (l15 & 7)) * 8;
            bf16x8 af[4], bfr[4];
#pragma unroll
            for (int mi = 0; mi < 4; mi++)
                af[mi] = *(const bf16x8*)&As[(wm + mi * 16 + l15) * 64 + xk];
#pragma unroll
            for (int nj = 0; nj < 4; nj++)
                bfr[nj] = *(const bf16x8*)&Bs[(wn + nj * 16 + l15) * 64 + xk];
#pragma unroll
            for (int mi = 0; mi < 4; mi++)
#pragma unroll
                for (int nj = 0; nj < 4; nj++)
                    acc[mi][nj] = __builtin_amdgcn_mfma_f32_16x16x32_bf16(
                        af[mi], bfr[nj], acc[mi][nj], 0, 0, 0);
        }
    }
#pragma unroll
    for (int nj = 0; nj < 4; nj++) {
        const int n = n0 + wn + nj * 16 + l15;
        const float bv = bias[n];
        const int g = n >> 10, c = n & 1023;
        const int jblk = c >> 4, up = (c & 15) >> 1, u = c & 1;
#pragma unroll
        for (int mi = 0; mi < 4; mi++) {
            const int mb = m0 + wm + mi * 16 + q * 4;
            f32x4 v = acc[mi][nj];
            float vals[4] = {v.x, v.y, v.z, v.w};
#pragma unroll
            for (int k = 0; k < 4; k++) {
                const int m = mb + k;
                const int r = m >> 6, b = m & 63;
                const int bp = b >> 1, bb = b & 1;
                const int t = bp * 8 + up;
                C[(size_t)r * 262144 + jblk * 4096 + t * 16 + g * 4 + bb * 2 + u]
                    = f2bf(vals[k] + bv);
            }
        }
    }
}

__global__ void init_flags(unsigned* f) { if (threadIdx.x < 128) f[threadIdx.x] = 0; }

// ---------------- fused persistent pipeline ----------------
// 128 blocks: role 0 = L0 recurrence, role 1 = fused R1 (Wih1 fwd-proj + Whh1
// recurrence in one block). Flat per-block flag barrier. 4-slot rings via LLC.

__device__ __forceinline__ void load_wf(const u16* W, int j0, int w, int l15, int q,
                                        bf16x8 wf[4][8]) {
    const u16* wbase = W + (size_t)(j0 + l15) * HID + w * 256 + q * 8;
#pragma unroll
    for (int nt = 0; nt < 4; nt++)
#pragma unroll
        for (int ki = 0; ki < 8; ki++)
            wf[nt][ki] = *(const bf16x8*)(wbase + (size_t)nt * 1048576 + ki * 32);
}

// Recurrence mm: slab (agent-scope, LLC) x register-stationary weights.
// sched_barrier(0) pins ALL 64 slab loads above the MFMAs -> single burst.
__device__ __forceinline__ void mm_ring(const u16* slab, const bf16x8 wf[4][8],
                                        int w, int l15, int q, f32x4 acc[4][4]) {
    union BU { ull v[2]; bf16x8 f; };
    BU st[4][8];
    const u16* arow = slab + (size_t)l15 * HID + w * 256 + q * 8;
#pragma unroll
    for (int ki = 0; ki < 8; ki++)
#pragma unroll
        for (int mt = 0; mt < 4; mt++) {
            const ull* p = (const ull*)(arow + mt * 16384 + ki * 32);
            st[mt][ki].v[0] = ld8(p);
            st[mt][ki].v[1] = ld8(p + 1);
        }
    __builtin_amdgcn_sched_barrier(0);
#pragma unroll
    for (int ki = 0; ki < 8; ki++)
#pragma unroll
        for (int mt = 0; mt < 4; mt++)
#pragma unroll
            for (int nt = 0; nt < 4; nt++)
                acc[mt][nt] = __builtin_amdgcn_mfma_f32_16x16x32_bf16(
                    st[mt][ki].f, wf[nt][ki], acc[mt][nt], 0, 0, 0);
}

// Forward mm (off the recurrence-critical path): slab agent-scope burst,
// weights streamed per-ki from XCD-private L2 (plain cached loads).
__device__ __forceinline__ void mm_fwd(const u16* slab, const u16* W, int j0,
                                       int w, int l15, int q, f32x4 acc[4][4]) {
    union BU { ull v[2]; bf16x8 f; };
    BU st[4][8];
    const u16* arow = slab + (size_t)l15 * HID + w * 256 + q * 8;
    const u16* wbase = W + (size_t)(j0 + l15) * HID + w * 256 + q * 8;
#pragma unroll
    for (int ki = 0; ki < 8; ki++)
#pragma unroll
        for (int mt = 0; mt < 4; mt++) {
            const ull* p = (const ull*)(arow + mt * 16384 + ki * 32);
            st[mt][ki].v[0] = ld8(p);
            st[mt][ki].v[1] = ld8(p + 1);
        }
#pragma unroll
    for (int ki = 0; ki < 8; ki++) {
        bf16x8 wfk[4];
#pragma unroll
        for (int nt = 0; nt < 4; nt++)
            wfk[nt] = *(const bf16x8*)(wbase + (size_t)nt * 1048576 + ki * 32);
#pragma unroll
        for (int mt = 0; mt < 4; mt++)
#pragma unroll
            for (int nt = 0; nt < 4; nt++)
                acc[mt][nt] = __builtin_amdgcn_mfma_f32_16x16x32_bf16(
                    st[mt][ki].f, wfk[nt], acc[mt][nt], 0, 0, 0);
    }
}

__device__ __forceinline__ void store_P(const f32x4 acc[4][4], int w, int l15, int q,
                                        float (*P)[64][68]) {
#pragma unroll
    for (int mt = 0; mt < 4; mt++)
#pragma unroll
        for (int nt = 0; nt < 4; nt++)
            *(f32x4*)&P[w][nt * 16 + l15][mt * 16 + q * 4] = acc[mt][nt];
}

// wave 0 polls F0 >= n0, wave 1 polls Fr >= nr (when > 0); then block barrier.
__device__ __forceinline__ void wait2(const unsigned* F0, const unsigned* Fr,
                                      int n0, int nr, int w, int ln, int* abortf) {
    const unsigned* A = (w == 0) ? F0 : Fr;
    const int need = (w == 0) ? n0 : nr;
    if (w < 2 && need > 0 && *abortf == 0) {
        int it = 0;
        while ((int)ld4(&A[ln]) < need) {
            if (++it > 20000000) { *abortf = 1; break; }
        }
    }
    __syncthreads();
}

__launch_bounds__(256, 1)
__global__ void pipeline(const u16* __restrict__ wb, const u16* __restrict__ Xp,
                         const float* __restrict__ b1, float* __restrict__ out,
                         u16* __restrict__ ring0, u16* __restrict__ ring1,
                         unsigned* __restrict__ flags) {
    __shared__ float P[4][64][68];
    __shared__ int abortf;
    const int tid = threadIdx.x;
    if (tid == 0) abortf = 0;
    const int w = tid >> 6, ln = tid & 63;
    const int l15 = ln & 15, q = ln >> 4;
    const int bid = blockIdx.x;
    const int role = bid >> 6;
    const int jblk = bid & 63;
    const int j0 = jblk * 16;
    unsigned* F0 = flags;
    unsigned* Fr = flags + 64;
    __syncthreads();

    if (role == 0) {
        // ---------------- L0: h0(r) = lstm(Whh0 @ h0(r-1) + Xp(r)) ----------------
        bf16x8 wf[4][8];
        load_wf(wb + WB_WHH0, j0, w, l15, q, wf);
        const int up = tid & 7, bp = tid >> 3;
        float cst[2][2] = {{0.f, 0.f}, {0.f, 0.f}};
        for (int r = 0; r < 512; ++r) {
            // coalesced packed Xp prefetch: 32 B per thread (overlaps the poll)
            ull xq[4];
            const ull* xp8 = (const ull*)(Xp + (size_t)r * 262144 + jblk * 4096 + tid * 16);
#pragma unroll
            for (int gg = 0; gg < 4; gg++) xq[gg] = xp8[gg];
            // peers done r-1; fused-R1 consumed ring0 slot r&3 (its step r-4)
            wait2(F0, Fr, r, r - 3, w, ln, &abortf);
            if (r > 0) {
                f32x4 acc[4][4];
#pragma unroll
                for (int i = 0; i < 4; i++)
#pragma unroll
                    for (int j = 0; j < 4; j++) acc[i][j] = 0.f;
                mm_ring(ring0 + (size_t)((r - 1) & 3) * 65536, wf, w, l15, q, acc);
                store_P(acc, w, l15, q, P);
            }
            __syncthreads();
            f32x2 pre[4][2];
#pragma unroll
            for (int gg = 0; gg < 4; gg++)
#pragma unroll
                for (int u = 0; u < 2; u++) {
                    if (r > 0) {
                        const int col = gg * 16 + up * 2 + u;
                        f32x2 s = *(const f32x2*)&P[0][col][bp * 2];
                        s += *(const f32x2*)&P[1][col][bp * 2];
                        s += *(const f32x2*)&P[2][col][bp * 2];
                        s += *(const f32x2*)&P[3][col][bp * 2];
                        pre[gg][u] = s;
                    } else pre[gg][u] = 0.f;
                }
            u16* hout = ring0 + (size_t)(r & 3) * 65536;
#pragma unroll
            for (int bb = 0; bb < 2; bb++) {
                const int b = bp * 2 + bb;
                float hn[2], cn[2];
#pragma unroll
                for (int u = 0; u < 2; u++) {
                    const float pi = pre[0][u][bb] + xpick(xq[0], bb, u);
                    const float pf = pre[1][u][bb] + xpick(xq[1], bb, u) + 1.0f;
                    const float pg = pre[2][u][bb] + xpick(xq[2], bb, u);
                    const float po = pre[3][u][bb] + xpick(xq[3], bb, u);
                    const float cnew = sigm(pf) * cst[bb][u] + sigm(pi) * tanh_f(pg);
                    cst[bb][u] = cnew;
                    hn[u] = sigm(po) * tanh_f(cnew);
                    cn[u] = cnew;
                }
                const unsigned hw = (unsigned)f2bf(hn[0]) | ((unsigned)f2bf(hn[1]) << 16);
                st4((unsigned*)(hout + (size_t)b * HID + j0 + up * 2), hw);
                if (r == 511) {
                    f32x2 h2 = {hn[0], hn[1]}, c2 = {cn[0], cn[1]};
                    *(f32x2*)&out[OUT_H_OFF + (size_t)b * HID + j0 + up * 2] = h2;
                    *(f32x2*)&out[OUT_C_OFF + (size_t)b * HID + j0 + up * 2] = c2;
                }
            }
            __syncthreads();
            if (tid == 0) st4(&F0[jblk], (unsigned)(r + 1));
        }
    } else {
        // ------- R1 fused: h1(t) = lstm(Wih1@h0(t) + Whh1@h1(t-1) + b1) -------
        bf16x8 wf[4][8];
        load_wf(wb + WB_WHH1, j0, w, l15, q, wf);
        const int up = tid & 7, bp = tid >> 3;
        float bv[4][2];
#pragma unroll
        for (int gg = 0; gg < 4; gg++)
#pragma unroll
            for (int u = 0; u < 2; u++)
                bv[gg][u] = b1[gg * 1024 + j0 + up * 2 + u];
        float cst[2][2] = {{0.f, 0.f}, {0.f, 0.f}};
        f32x4 acc[4][4];
#pragma unroll
        for (int i = 0; i < 4; i++)
#pragma unroll
            for (int j = 0; j < 4; j++) acc[i][j] = 0.f;
        // prologue: forward-proj for t=0 (h0(0) in ring0 slot 0)
        wait2(F0, Fr, 1, 0, w, ln, &abortf);
        mm_fwd(ring0, wb + WB_WIH1, j0, w, l15, q, acc);
        for (int t = 0; t < 512; ++t) {
            // peers done t-1 -> ring1 slab (t-1)&3 ready (and slot t&3 reusable)
            wait2(F0, Fr, 0, t, w, ln, &abortf);
            if (t > 0)
                mm_ring(ring1 + (size_t)((t - 1) & 3) * 65536, wf, w, l15, q, acc);
            store_P(acc, w, l15, q, P);
            __syncthreads();
            f32x2 pre[4][2];
#pragma unroll
            for (int gg = 0; gg < 4; gg++)
#pragma unroll
                for (int u = 0; u < 2; u++) {
                    const int col = gg * 16 + up * 2 + u;
                    f32x2 s = *(const f32x2*)&P[0][col][bp * 2];
                    s += *(const f32x2*)&P[1][col][bp * 2];
                    s += *(const f32x2*)&P[2][col][bp * 2];
                    s += *(const f32x2*)&P[3][col][bp * 2];
                    s += bv[gg][u];
                    pre[gg][u] = s;
                }
            u16* hout = ring1 + (size_t)(t & 3) * 65536;
#pragma unroll
            for (int bb = 0; bb < 2; bb++) {
                const int b = bp * 2 + bb;
                float hn[2], cn[2];
#pragma unroll
                for (int u = 0; u < 2; u++) {
                    const float pi = pre[0][u][bb];
                    const float pf = pre[1][u][bb] + 1.0f;
                    const float pg = pre[2][u][bb];
                    const float po = pre[3][u][bb];
                    const float cnew = sigm(pf) * cst[bb][u] + sigm(pi) * tanh_f(pg);
                    cst[bb][u] = cnew;
                    hn[u] = sigm(po) * tanh_f(cnew);
                    cn[u] = cnew;
                }
                const unsigned hw = (unsigned)f2bf(hn[0]) | ((unsigned)f2bf(hn[1]) << 16);
                st4((unsigned*)(hout + (size_t)b * HID + j0 + up * 2), hw);
                f32x2 g2 = {hn[0], hn[1]};
                *(f32x2*)&out[(size_t)b * 524288 + (size_t)t * 1024 + j0 + up * 2] = g2;
                if (t == 511) {
                    f32x2 h2 = {hn[0], hn[1]}, c2 = {cn[0], cn[1]};
                    *(f32x2*)&out[OUT_H_OFF + 65536 + (size_t)b * HID + j0 + up * 2] = h2;
                    *(f32x2*)&out[OUT_C_OFF + 65536 + (size_t)b * HID + j0 + up * 2] = c2;
                }
            }
            __syncthreads();
            if (tid == 0) st4(&Fr[jblk], (unsigned)(t + 1));
            // forward-proj for t+1 (overlaps peers' discovery + their mm)
            if (t < 511) {
                wait2(F0, Fr, t + 2, 0, w, ln, &abortf);
#pragma unroll
                for (int i = 0; i < 4; i++)
#pragma unroll
                    for (int j = 0; j < 4; j++) acc[i][j] = 0.f;
                mm_fwd(ring0 + (size_t)((t + 1) & 3) * 65536, wb + WB_WIH1, j0,
                       w, l15, q, acc);
            }
        }
    }
}

__global__ void diag(float* o, float v) { o[0] = v; }

extern "C" void kernel_launch(void* const* d_in, const int* in_sizes, int n_in,
                              void* d_out, int out_size, void* d_ws, size_t ws_size,
                              hipStream_t stream) {
    const int*   y    = (const int*)  d_in[0];
    const float* Emb  = (const float*)d_in[1];
    const float* Wih0 = (const float*)d_in[2];
    const float* Whh0 = (const float*)d_in[3];
    const float* b0   = (const float*)d_in[4];
    const float* Wih1 = (const float*)d_in[5];
    const float* Whh1 = (const float*)d_in[6];
    const float* b1   = (const float*)d_in[7];
    float* out = (float*)d_out;
    char* wsb = (char*)d_ws;

    if (ws_size < WS_NEEDED) {
        diag<<<1, 1, 0, stream>>>(out, (float)(ws_size >> 20));
        return;
    }

    u16* wb   = (u16*)wsb;
    u16* X    = (u16*)(wsb + WS_X_OFF);
    u16* Xp   = (u16*)(wsb + WS_XP_OFF);
    u16* ring0 = (u16*)(wsb + RING0_B);
    u16* ring1 = (u16*)(wsb + RING1_B);
    unsigned* flags = (unsigned*)(wsb + FLAGS_B);

    prep_weights<<<1024, 256, 0, stream>>>(Wih0, Whh0, Wih1, Whh1, wb);
    gather_x<<<MTOK, 256, 0, stream>>>(y, Emb, X);
    gemm_bt<<<dim3(32, 256), 256, 0, stream>>>(X, wb + WB_WIH0, b0, Xp, MTOK, 4096, HID);
    init_flags<<<1, 256, 0, stream>>>(flags);
    pipeline<<<128, 256, 0, stream>>>(wb, Xp, b1, out, ring0, ring1, flags);
}

// Round 4
// 6294.667 us; speedup vs baseline: 1.7698x; 1.7698x over previous
//
#include <hip/hip_runtime.h>
#include <hip/hip_bf16.h>

typedef unsigned short u16;
typedef unsigned long long ull;
typedef __attribute__((ext_vector_type(8))) short bf16x8;
typedef __attribute__((ext_vector_type(4))) float f32x4;
typedef __attribute__((ext_vector_type(2))) float f32x2;

// Problem sizes
#define HID 1024
#define BATCH 64
#define SEQ 512
#define MTOK 32768   // SEQ*BATCH

// Workspace layout (bytes)
#define WB_WIH0 0
#define WB_WHH0 4194304
#define WB_WIH1 8388608
#define WB_WHH1 12582912
#define WS_X_OFF   33554432ull           // X buffer (bf16, 32768x1024)
#define WS_XP_OFF  100663296ull          // Xproj layer0 (bf16, packed layout)
#define WS_NEEDED  369098752ull
// Rings + state overlay the Wih0 bf16 byte region [0, 8M), dead after gemm0:
#define RING0_B 0ull          // 4 slots x 64x1024 bf16 = 512 KB
#define RING1_B 524288ull     // 4 slots x 64x1024 bf16
#define XP1_B   1048576ull    // 4 slots x [64 jblk][256 tid][16] bf16 = 2 MB
#define C0_B    3145728ull    // L0 cell state, 64x1024 f32 = 256 KB
#define C1_B    3407872ull    // R1 cell state, 64x1024 f32 = 256 KB

// Output layout (fp32 elements)
#define OUT_H_OFF 33554432
#define OUT_C_OFF 33685504

// Packed per-thread gate-tile layout for Xp / xp1:
//   elem(r, jblk, tid, gg, bb, u) = r*262144 + jblk*4096 + tid*16 + gg*4 + bb*2 + u
// where consumer thread tid = bp*8+up handles batches bp*2+bb, cols j0+up*2+u.

__device__ __forceinline__ u16 f2bf(float f) {
    union { float f; unsigned u; } x; x.f = f;
    unsigned r = (x.u + 0x7FFFu + ((x.u >> 16) & 1u)) >> 16;
    return (u16)r;
}
__device__ __forceinline__ float bf2f(u16 v) {
    union { unsigned u; float f; } x; x.u = ((unsigned)v) << 16;
    return x.f;
}
__device__ __forceinline__ float fexp2(float x) { return __builtin_amdgcn_exp2f(x); }
__device__ __forceinline__ float frcp(float x) { return __builtin_amdgcn_rcpf(x); }
__device__ __forceinline__ float sigm(float x) {
    return frcp(1.f + fexp2(x * -1.4426950408889634f));
}
__device__ __forceinline__ float tanh_f(float x) {
    return 1.f - 2.f * frcp(fexp2(x * 2.8853900817779268f) + 1.f);
}
__device__ __forceinline__ float xpick(ull q, int bb, int u) {
    return bf2f((u16)(q >> ((bb * 2 + u) << 4)));
}
__device__ __forceinline__ void ldsload16(const u16* g, u16* l) {
    __builtin_amdgcn_global_load_lds(
        (__attribute__((address_space(1))) void*)(unsigned long long)(const char*)g,
        (__attribute__((address_space(3))) void*)l, 16, 0, 0);
}

// ---------------- prep: weights fp32->bf16 ----------------
__launch_bounds__(256)
__global__ void prep_weights(const float* __restrict__ a, const float* __restrict__ b,
                             const float* __restrict__ c, const float* __restrict__ d,
                             u16* __restrict__ dst) {
    const int gtid = blockIdx.x * 256 + threadIdx.x;
#pragma unroll
    for (int k = 0; k < 16; k++) {
        const float* s = (k < 4) ? a : (k < 8) ? b : (k < 12) ? c : d;
        const int off = ((k & 3) * 262144 + gtid) * 4;
        float4 v = *(const float4*)(s + off);
        ushort4 o;
        o.x = f2bf(v.x); o.y = f2bf(v.y); o.z = f2bf(v.z); o.w = f2bf(v.w);
        *(ushort4*)(dst + (size_t)(k >> 2) * 4194304 + off) = o;
    }
}

// ---------------- embedding gather ----------------
__launch_bounds__(256)
__global__ void gather_x(const int* __restrict__ y, const float* __restrict__ E,
                         u16* __restrict__ X) {
    const int m = blockIdx.x;
    const int t = m >> 6, b = m & 63;
    const int idx = y[b * SEQ + t];
    const float4 v = *(const float4*)(E + (size_t)idx * HID + threadIdx.x * 4);
    ushort4 o;
    o.x = f2bf(v.x); o.y = f2bf(v.y); o.z = f2bf(v.z); o.w = f2bf(v.w);
    *(ushort4*)(X + (size_t)m * HID + threadIdx.x * 4) = o;
}

// ---------------- big GEMM (layer0 input projection) ----------------
// Writes C in the packed per-thread layout consumed by the L0 recurrence.
__launch_bounds__(256, 3)
__global__ void gemm_bt(const u16* __restrict__ A, const u16* __restrict__ Bm,
                        const float* __restrict__ bias, u16* __restrict__ C,
                        int M, int N, int K) {
    __shared__ u16 As[128 * 64];
    __shared__ u16 Bs[128 * 64];
    const int tid = threadIdx.x;
    const int ln = tid & 63;
    const int l15 = ln & 15, q = ln >> 4;
    const int w = tid >> 6;
    const int wm = (w & 1) * 64, wn = (w >> 1) * 64;
    const int m0 = blockIdx.y * 128, n0 = blockIdx.x * 128;

    f32x4 acc[4][4];
#pragma unroll
    for (int i = 0; i < 4; i++)
#pragma unroll
        for (int j = 0; j < 4; j++) acc[i][j] = 0.f;

    const int srow = tid >> 3;
    const int spk = tid & 7;
    const u16* gA = A + (size_t)m0 * K;
    const u16* gB = Bm + (size_t)n0 * K;
    const int wbase = (tid & 0xC0) * 8;

    const int kIters = K >> 6;
    for (int kt = 0; kt < kIters; kt++) {
        const int k0 = kt << 6;
        __syncthreads();
#pragma unroll
        for (int i = 0; i < 4; i++) {
            const int row = i * 32 + srow;
            const int kb = spk ^ (row & 7);
            ldsload16(gA + (size_t)row * K + k0 + kb * 8, &As[i * 2048 + wbase]);
            ldsload16(gB + (size_t)row * K + k0 + kb * 8, &Bs[i * 2048 + wbase]);
        }
        __syncthreads();
#pragma unroll
        for (int s = 0; s < 2; s++) {
            const int xk = ((s * 4 + q) ^ (l15 & 7)) * 8;
            bf16x8 af[4], bfr[4];
#pragma unroll
            for (int mi = 0; mi < 4; mi++)
                af[mi] = *(const bf16x8*)&As[(wm + mi * 16 + l15) * 64 + xk];
#pragma unroll
            for (int nj = 0; nj < 4; nj++)
                bfr[nj] = *(const bf16x8*)&Bs[(wn + nj * 16 + l15) * 64 + xk];
#pragma unroll
            for (int mi = 0; mi < 4; mi++)
#pragma unroll
                for (int nj = 0; nj < 4; nj++)
                    acc[mi][nj] = __builtin_amdgcn_mfma_f32_16x16x32_bf16(
                        af[mi], bfr[nj], acc[mi][nj], 0, 0, 0);
        }
    }
#pragma unroll
    for (int nj = 0; nj < 4; nj++) {
        const int n = n0 + wn + nj * 16 + l15;
        const float bv = bias[n];
        const int g = n >> 10, c = n & 1023;
        const int jblk = c >> 4, up = (c & 15) >> 1, u = c & 1;
#pragma unroll
        for (int mi = 0; mi < 4; mi++) {
            const int mb = m0 + wm + mi * 16 + q * 4;
            f32x4 v = acc[mi][nj];
            float vals[4] = {v.x, v.y, v.z, v.w};
#pragma unroll
            for (int k = 0; k < 4; k++) {
                const int m = mb + k;
                const int r = m >> 6, b = m & 63;
                const int bp = b >> 1, bb = b & 1;
                const int t = bp * 8 + up;
                C[(size_t)r * 262144 + jblk * 4096 + t * 16 + g * 4 + bb * 2 + u]
                    = f2bf(vals[k] + bv);
            }
        }
    }
}

// ---------------- per-timestep kernel (node-sequenced pipeline) ----------------
// Node r: 64 blocks L0 step r | 64 blocks P1 step r-1 | 64 blocks R1 step r-2.
// Ordering between nodes comes from stream order (device-scope release at
// kernel end) -> ALL memory ops are plain, L2-cached. No flags, no atomics.

__device__ __forceinline__ void load_wf(const u16* W, int j0, int w, int l15, int q,
                                        bf16x8 wf[4][8]) {
    const u16* wbase = W + (size_t)(j0 + l15) * HID + w * 256 + q * 8;
#pragma unroll
    for (int nt = 0; nt < 4; nt++)
#pragma unroll
        for (int ki = 0; ki < 8; ki++)
            wf[nt][ki] = *(const bf16x8*)(wbase + (size_t)nt * 1048576 + ki * 32);
}

// slab (64x1024 bf16, L2-cached plain loads) x register weights -> acc
__device__ __forceinline__ void mm_plain(const u16* slab, const bf16x8 wf[4][8],
                                         int w, int l15, int q, f32x4 acc[4][4]) {
    bf16x8 st[4][8];
    const u16* arow = slab + (size_t)l15 * HID + w * 256 + q * 8;
#pragma unroll
    for (int ki = 0; ki < 8; ki++)
#pragma unroll
        for (int mt = 0; mt < 4; mt++)
            st[mt][ki] = *(const bf16x8*)(arow + (size_t)mt * 16384 + ki * 32);
    __builtin_amdgcn_sched_barrier(0);
#pragma unroll
    for (int ki = 0; ki < 8; ki++)
#pragma unroll
        for (int mt = 0; mt < 4; mt++)
#pragma unroll
            for (int nt = 0; nt < 4; nt++)
                acc[mt][nt] = __builtin_amdgcn_mfma_f32_16x16x32_bf16(
                    st[mt][ki], wf[nt][ki], acc[mt][nt], 0, 0, 0);
}

__device__ __forceinline__ void store_P(const f32x4 acc[4][4], int w, int l15, int q,
                                        float (*P)[64][68]) {
#pragma unroll
    for (int mt = 0; mt < 4; mt++)
#pragma unroll
        for (int nt = 0; nt < 4; nt++)
            *(f32x4*)&P[w][nt * 16 + l15][mt * 16 + q * 4] = acc[mt][nt];
}

__launch_bounds__(256)
__global__ void step_k(int r, const u16* __restrict__ wb, const u16* __restrict__ Xp,
                       const float* __restrict__ b1, float* __restrict__ out,
                       u16* __restrict__ ring0, u16* __restrict__ ring1,
                       u16* __restrict__ xp1, float* __restrict__ c0st,
                       float* __restrict__ c1st) {
    __shared__ float P[4][64][68];
    const int tid = threadIdx.x;
    const int w = tid >> 6, ln = tid & 63;
    const int l15 = ln & 15, q = ln >> 4;
    const int bid = blockIdx.x;
    const int role = bid >> 6;
    const int jblk = bid & 63;
    const int j0 = jblk * 16;

    if (role == 0) {
        // ---------------- L0 step r: h0(r) = lstm(Whh0 @ h0(r-1) + Xp(r)) -------
        if (r > 511) return;
        const int up = tid & 7, bp = tid >> 3;
        // packed Xp: 32 B per thread, coalesced
        ull xq[4];
        const ull* xp8 = (const ull*)(Xp + (size_t)r * 262144 + jblk * 4096 + tid * 16);
#pragma unroll
        for (int gg = 0; gg < 4; gg++) xq[gg] = xp8[gg];
        f32x4 cin = {0.f, 0.f, 0.f, 0.f};
        if (r > 0) cin = *(const f32x4*)(c0st + ((size_t)jblk * 256 + tid) * 4);
        bf16x8 wf[4][8];
        load_wf(wb + WB_WHH0, j0, w, l15, q, wf);
        f32x4 acc[4][4];
#pragma unroll
        for (int i = 0; i < 4; i++)
#pragma unroll
            for (int j = 0; j < 4; j++) acc[i][j] = 0.f;
        if (r > 0)
            mm_plain(ring0 + (size_t)((r - 1) & 3) * 65536, wf, w, l15, q, acc);
        store_P(acc, w, l15, q, P);
        __syncthreads();
        f32x2 pre[4][2];
#pragma unroll
        for (int gg = 0; gg < 4; gg++)
#pragma unroll
            for (int u = 0; u < 2; u++) {
                if (r > 0) {
                    const int col = gg * 16 + up * 2 + u;
                    f32x2 s = *(const f32x2*)&P[0][col][bp * 2];
                    s += *(const f32x2*)&P[1][col][bp * 2];
                    s += *(const f32x2*)&P[2][col][bp * 2];
                    s += *(const f32x2*)&P[3][col][bp * 2];
                    pre[gg][u] = s;
                } else pre[gg][u] = 0.f;
            }
        float cst[2][2] = {{cin.x, cin.y}, {cin.z, cin.w}};
        u16* hout = ring0 + (size_t)(r & 3) * 65536;
#pragma unroll
        for (int bb = 0; bb < 2; bb++) {
            const int b = bp * 2 + bb;
            float hn[2], cn[2];
#pragma unroll
            for (int u = 0; u < 2; u++) {
                const float pi = pre[0][u][bb] + xpick(xq[0], bb, u);
                const float pf = pre[1][u][bb] + xpick(xq[1], bb, u) + 1.0f;
                const float pg = pre[2][u][bb] + xpick(xq[2], bb, u);
                const float po = pre[3][u][bb] + xpick(xq[3], bb, u);
                const float cnew = sigm(pf) * cst[bb][u] + sigm(pi) * tanh_f(pg);
                cst[bb][u] = cnew;
                hn[u] = sigm(po) * tanh_f(cnew);
                cn[u] = cnew;
            }
            const unsigned hw = (unsigned)f2bf(hn[0]) | ((unsigned)f2bf(hn[1]) << 16);
            *(unsigned*)(hout + (size_t)b * HID + j0 + up * 2) = hw;
            if (r == 511) {
                f32x2 h2 = {hn[0], hn[1]}, c2 = {cn[0], cn[1]};
                *(f32x2*)&out[OUT_H_OFF + (size_t)b * HID + j0 + up * 2] = h2;
                *(f32x2*)&out[OUT_C_OFF + (size_t)b * HID + j0 + up * 2] = c2;
            }
        }
        f32x4 cout = {cst[0][0], cst[0][1], cst[1][0], cst[1][1]};
        *(f32x4*)(c0st + ((size_t)jblk * 256 + tid) * 4) = cout;
    } else if (role == 1) {
        // ------- P1 step r-1: xp1(r-1) = Wih1 @ h0(r-1) + b1, packed -------
        if (r < 1 || r > 512) return;
        const int up = tid & 7, bp = tid >> 3;
        float bv[4][2];
#pragma unroll
        for (int gg = 0; gg < 4; gg++)
#pragma unroll
            for (int u = 0; u < 2; u++)
                bv[gg][u] = b1[gg * 1024 + j0 + up * 2 + u];
        bf16x8 wf[4][8];
        load_wf(wb + WB_WIH1, j0, w, l15, q, wf);
        f32x4 acc[4][4];
#pragma unroll
        for (int i = 0; i < 4; i++)
#pragma unroll
            for (int j = 0; j < 4; j++) acc[i][j] = 0.f;
        mm_plain(ring0 + (size_t)((r - 1) & 3) * 65536, wf, w, l15, q, acc);
        store_P(acc, w, l15, q, P);
        __syncthreads();
        ull* xo8 = (ull*)(xp1 + (size_t)((r - 1) & 3) * 262144 + jblk * 4096 + tid * 16);
        ull ow[4];
#pragma unroll
        for (int gg = 0; gg < 4; gg++) {
            ow[gg] = 0;
#pragma unroll
            for (int u = 0; u < 2; u++) {
                const int col = gg * 16 + up * 2 + u;
                f32x2 s = *(const f32x2*)&P[0][col][bp * 2];
                s += *(const f32x2*)&P[1][col][bp * 2];
                s += *(const f32x2*)&P[2][col][bp * 2];
                s += *(const f32x2*)&P[3][col][bp * 2];
#pragma unroll
                for (int bb = 0; bb < 2; bb++) {
                    const float val = s[bb] + bv[gg][u];
                    ow[gg] |= (ull)f2bf(val) << ((bb * 2 + u) << 4);
                }
            }
        }
#pragma unroll
        for (int gg = 0; gg < 4; gg++) xo8[gg] = ow[gg];
    } else {
        // ------- R1 step t=r-2: h1(t) = lstm(Whh1 @ h1(t-1) + xp1(t)) -------
        if (r < 2) return;
        const int t = r - 2;
        const int up = tid & 7, bp = tid >> 3;
        ull xq[4];
        const ull* xp8 = (const ull*)(xp1 + (size_t)(t & 3) * 262144 + jblk * 4096 + tid * 16);
#pragma unroll
        for (int gg = 0; gg < 4; gg++) xq[gg] = xp8[gg];
        f32x4 cin = {0.f, 0.f, 0.f, 0.f};
        if (t > 0) cin = *(const f32x4*)(c1st + ((size_t)jblk * 256 + tid) * 4);
        bf16x8 wf[4][8];
        load_wf(wb + WB_WHH1, j0, w, l15, q, wf);
        f32x4 acc[4][4];
#pragma unroll
        for (int i = 0; i < 4; i++)
#pragma unroll
            for (int j = 0; j < 4; j++) acc[i][j] = 0.f;
        if (t > 0)
            mm_plain(ring1 + (size_t)((t - 1) & 3) * 65536, wf, w, l15, q, acc);
        store_P(acc, w, l15, q, P);
        __syncthreads();
        f32x2 pre[4][2];
#pragma unroll
        for (int gg = 0; gg < 4; gg++)
#pragma unroll
            for (int u = 0; u < 2; u++) {
                if (t > 0) {
                    const int col = gg * 16 + up * 2 + u;
                    f32x2 s = *(const f32x2*)&P[0][col][bp * 2];
                    s += *(const f32x2*)&P[1][col][bp * 2];
                    s += *(const f32x2*)&P[2][col][bp * 2];
                    s += *(const f32x2*)&P[3][col][bp * 2];
                    pre[gg][u] = s;
                } else pre[gg][u] = 0.f;
            }
        float cst[2][2] = {{cin.x, cin.y}, {cin.z, cin.w}};
        u16* hout = ring1 + (size_t)(t & 3) * 65536;
#pragma unroll
        for (int bb = 0; bb < 2; bb++) {
            const int b = bp * 2 + bb;
            float hn[2], cn[2];
#pragma unroll
            for (int u = 0; u < 2; u++) {
                const float pi = pre[0][u][bb] + xpick(xq[0], bb, u);
                const float pf = pre[1][u][bb] + xpick(xq[1], bb, u) + 1.0f;
                const float pg = pre[2][u][bb] + xpick(xq[2], bb, u);
                const float po = pre[3][u][bb] + xpick(xq[3], bb, u);
                const float cnew = sigm(pf) * cst[bb][u] + sigm(pi) * tanh_f(pg);
                cst[bb][u] = cnew;
                hn[u] = sigm(po) * tanh_f(cnew);
                cn[u] = cnew;
            }
            const unsigned hw = (unsigned)f2bf(hn[0]) | ((unsigned)f2bf(hn[1]) << 16);
            *(unsigned*)(hout + (size_t)b * HID + j0 + up * 2) = hw;
            f32x2 g2 = {hn[0], hn[1]};
            *(f32x2*)&out[(size_t)b * 524288 + (size_t)t * 1024 + j0 + up * 2] = g2;
            if (t == 511) {
                f32x2 h2 = {hn[0], hn[1]}, c2 = {cn[0], cn[1]};
                *(f32x2*)&out[OUT_H_OFF + 65536 + (size_t)b * HID + j0 + up * 2] = h2;
                *(f32x2*)&out[OUT_C_OFF + 65536 + (size_t)b * HID + j0 + up * 2] = c2;
            }
        }
        f32x4 cout = {cst[0][0], cst[0][1], cst[1][0], cst[1][1]};
        *(f32x4*)(c1st + ((size_t)jblk * 256 + tid) * 4) = cout;
    }
}

__global__ void diag(float* o, float v) { o[0] = v; }

extern "C" void kernel_launch(void* const* d_in, const int* in_sizes, int n_in,
                              void* d_out, int out_size, void* d_ws, size_t ws_size,
                              hipStream_t stream) {
    const int*   y    = (const int*)  d_in[0];
    const float* Emb  = (const float*)d_in[1];
    const float* Wih0 = (const float*)d_in[2];
    const float* Whh0 = (const float*)d_in[3];
    const float* b0   = (const float*)d_in[4];
    const float* Wih1 = (const float*)d_in[5];
    const float* Whh1 = (const float*)d_in[6];
    const float* b1   = (const float*)d_in[7];
    float* out = (float*)d_out;
    char* wsb = (char*)d_ws;

    if (ws_size < WS_NEEDED) {
        diag<<<1, 1, 0, stream>>>(out, (float)(ws_size >> 20));
        return;
    }

    u16* wb   = (u16*)wsb;
    u16* X    = (u16*)(wsb + WS_X_OFF);
    u16* Xp   = (u16*)(wsb + WS_XP_OFF);
    u16* ring0 = (u16*)(wsb + RING0_B);
    u16* ring1 = (u16*)(wsb + RING1_B);
    u16* xp1   = (u16*)(wsb + XP1_B);
    float* c0st = (float*)(wsb + C0_B);
    float* c1st = (float*)(wsb + C1_B);

    prep_weights<<<1024, 256, 0, stream>>>(Wih0, Whh0, Wih1, Whh1, wb);
    gather_x<<<MTOK, 256, 0, stream>>>(y, Emb, X);
    gemm_bt<<<dim3(32, 256), 256, 0, stream>>>(X, wb + WB_WIH0, b0, Xp, MTOK, 4096, HID);
    for (int r = 0; r < 514; ++r)
        step_k<<<192, 256, 0, stream>>>(r, wb, Xp, b1, out, ring0, ring1, xp1,
                                        c0st, c1st);
}